// Round 7
// baseline (99.162 us; speedup 1.0000x reference)
//
#include <hip/hip_runtime.h>

#define OUTS 7
#define CC 256
#define HH 56
#define WW 56
#define PX (HH * WW)   // 3136
#define STRIDE 57      // padded row stride (float4 px): bank-quad=(x+y)%8, decorrelated
#define SPLIT 2        // ROI-list split across sibling blocks
#define MAXROI 96      // >= +12 sigma of Binomial(256, 1/8); list build guarded

// One block per (image n, channel-QUAD, roi-chunk s). Four planes staged
// zipped as float4-per-pixel: one ds_read_b128 + 4 fmax yields 4 outputs.
// Per-ROI bin edges precomputed once per block (packed u8 pairs in ushort).
// Lane = bin (0..48), one ROI per wave-pass, deterministic ballot-compacted
// ROI list (identical order across sibling blocks -- R4 lesson).
__global__ __launch_bounds__(256) void roipool_kernel(
    const float* __restrict__ images, const float* __restrict__ rois,
    const int* __restrict__ roi_idx, float* __restrict__ out, int R)
{
    __shared__ float4 plane4[STRIDE * HH];          // 51072 B
    __shared__ int    list[MAXROI];
    __shared__ unsigned short ys[MAXROI * 7];       // sy | ey<<8
    __shared__ unsigned short xs[MAXROI * 7];       // sx | ex<<8
    __shared__ int cnt;

    const int b  = blockIdx.x;
    const int s  = b & (SPLIT - 1);
    const int pq = b >> 1;             // n*64 + cquad
    const int n  = pq >> 6;
    const int c0 = (pq & 63) * 4;
    const int t  = threadIdx.x;

    // Deterministic ascending-r compaction (wave 0 only).
    if (t < 64) {
        int base = 0;
        #pragma unroll
        for (int k = 0; k < 4; ++k) {
            int r = k * 64 + t;
            bool match = (r < R) && (roi_idx[r] == n);
            unsigned long long mask = __ballot(match);
            int pos = base + __popcll(mask & ((1ULL << t) - 1ULL));
            if (match && pos < MAXROI) list[pos] = r;
            base += __popcll(mask);
        }
        if (t == 0) cnt = (base < MAXROI) ? base : MAXROI;
    }

    // Stage 4 planes zipped: plane4[y*57+x] = (c0,c1,c2,c3) at pixel (y,x).
    // 784 float4-groups; 56/4 == 14 groups/row so no group spans a row.
    const float* base0 = images + (size_t)(n * CC + c0) * PX;
    #pragma unroll
    for (int k = 0; k < 4; ++k) {
        int idx = t + k * 256;
        if (idx < PX / 4) {
            float4 a = reinterpret_cast<const float4*>(base0)[idx];
            float4 bb = reinterpret_cast<const float4*>(base0 + PX)[idx];
            float4 cc = reinterpret_cast<const float4*>(base0 + 2 * PX)[idx];
            float4 dd = reinterpret_cast<const float4*>(base0 + 3 * PX)[idx];
            int y  = idx / 14;
            int x0 = (idx - y * 14) * 4;
            float4* dst = &plane4[y * STRIDE + x0];
            dst[0] = make_float4(a.x, bb.x, cc.x, dd.x);
            dst[1] = make_float4(a.y, bb.y, cc.y, dd.y);
            dst[2] = make_float4(a.z, bb.z, cc.z, dd.z);
            dst[3] = make_float4(a.w, bb.w, cc.w, dd.w);
        }
    }
    __syncthreads();                   // covers list/cnt too

    const int count = cnt;

    // Per-ROI bin-edge tables, built once (count*7 <= 672 tasks).
    for (int e = t; e < count * 7; e += 256) {
        int m = e / 7, i = e - m * 7;
        int r = list[m];
        float4 rv = reinterpret_cast<const float4*>(rois)[r];
        int x1 = (int)floorf(rv.x * (float)WW);
        int y1 = (int)floorf(rv.y * (float)HH);
        int x2 = (int)ceilf (rv.z * (float)WW);
        int y2 = (int)ceilf (rv.w * (float)HH);
        int Hr = y2 - y1, Wr = x2 - x1;
        int sy = y1 + (i * Hr) / 7, ey = y1 + ((i + 1) * Hr + 6) / 7;
        int sx = x1 + (i * Wr) / 7, ex = x1 + ((i + 1) * Wr + 6) / 7;
        ys[m * 7 + i] = (unsigned short)(sy | (ey << 8));
        xs[m * 7 + i] = (unsigned short)(sx | (ex << 8));
    }
    __syncthreads();

    const int wv   = t >> 6;
    const int lane = t & 63;
    const int i = lane / 7;
    const int j = lane - i * 7;

    if (lane < OUTS * OUTS) {
        // (chunk s, wave wv) takes list positions m % 8 == s + 2*wv.
        for (int m = (wv << 1) + s; m < count; m += SPLIT * 4) {
            int r = list[m];
            int yse = ys[m * 7 + i];
            int xse = xs[m * 7 + j];
            int sy = yse & 255, ey = yse >> 8;
            int sx = xse & 255, ex = xse >> 8;

            float a0 = -3.402823466e+38f;   // finfo(float32).min
            float a1 = a0, a2 = a0, a3 = a0;
            const float4* rowp = &plane4[sy * STRIDE];
            for (int y = sy; y < ey; ++y, rowp += STRIDE) {
                for (int x = sx; x < ex; ++x) {
                    float4 v = rowp[x];     // ds_read_b128: 4 channels
                    a0 = fmaxf(a0, v.x);
                    a1 = fmaxf(a1, v.y);
                    a2 = fmaxf(a2, v.z);
                    a3 = fmaxf(a3, v.w);
                }
            }
            size_t o = ((size_t)r * CC + c0) * (OUTS * OUTS) + lane;
            out[o]       = a0;
            out[o + 49]  = a1;
            out[o + 98]  = a2;
            out[o + 147] = a3;
        }
    }
}

extern "C" void kernel_launch(void* const* d_in, const int* in_sizes, int n_in,
                              void* d_out, int out_size, void* d_ws, size_t ws_size,
                              hipStream_t stream) {
    const float* images  = (const float*)d_in[0];
    const float* rois    = (const float*)d_in[1];
    const int*   roi_idx = (const int*)d_in[2];
    float* out = (float*)d_out;

    int R = in_sizes[2];                         // 256
    int N = in_sizes[0] / (CC * HH * WW);        // 8

    int grid = N * (CC / 4) * SPLIT;             // 1024 blocks
    roipool_kernel<<<grid, 256, 0, stream>>>(images, rois, roi_idx, out, R);
}

// Round 8
// 90.252 us; speedup vs baseline: 1.0987x; 1.0987x over previous
//
#include <hip/hip_runtime.h>

#define OUTS 7
#define CC 256
#define HH 56
#define WW 56
#define PX (HH * WW)   // 3136
#define STRIDE 58      // float2 row stride: even (keeps 16B staging alignment),
                       // decorrelates banks vs 56 (same-column lanes spread out)
#define SPLIT 2        // ROI-list split across sibling blocks
#define MAXROI 96      // list capacity guard

// One block per (image n, channel-PAIR, roi-chunk s). R6 structure (float2
// zip, ~26 KB LDS -> 5 blocks/CU for latency hiding) + R8 change: the bin
// rectangle is scanned in 2-row x 4-col chunks with index-CLAMPED loads --
// 8 independent ds_read_b64 in flight per chain step (vs 1 in the rolled
// loop). Redundant clamped reads duplicate pixels, which is harmless under
// max. R7 lesson: big LDS (54 KB quad) killed occupancy and exposed the
// ds_read latency chain; keep LDS small, buy ILP instead.
__global__ __launch_bounds__(256) void roipool_kernel(
    const float* __restrict__ images, const float* __restrict__ rois,
    const int* __restrict__ roi_idx, float* __restrict__ out, int R)
{
    __shared__ __align__(16) float2 plane2[STRIDE * HH];  // 25984 B
    __shared__ int    list[MAXROI];
    __shared__ unsigned short ys[MAXROI * 7];   // sy | ey<<8
    __shared__ unsigned short xs[MAXROI * 7];   // sx | ex<<8
    __shared__ int cnt;

    const int b  = blockIdx.x;
    const int s  = b & (SPLIT - 1);
    const int pp = b >> 1;             // n*128 + cpair
    const int n  = pp >> 7;
    const int c0 = (pp & 127) * 2;
    const int t  = threadIdx.x;

    // Deterministic ascending-r compaction (wave 0 only) -- identical list
    // order across sibling blocks (atomicAdd order is not; R4 bug).
    if (t < 64) {
        int base = 0;
        #pragma unroll
        for (int k = 0; k < 4; ++k) {
            int r = k * 64 + t;
            bool match = (r < R) && (roi_idx[r] == n);
            unsigned long long mask = __ballot(match);
            int pos = base + __popcll(mask & ((1ULL << t) - 1ULL));
            if (match && pos < MAXROI) list[pos] = r;
            base += __popcll(mask);
        }
        if (t == 0) cnt = (base < MAXROI) ? base : MAXROI;
    }

    // Stage 2 planes zipped: plane2[y*58+x] = (cA, cB) at pixel (y,x).
    // 784 pixel-quads, 14 quads/row (56%4==0) -> no quad spans a row.
    const float4* srcA = reinterpret_cast<const float4*>(images + (size_t)(n * CC + c0)     * PX);
    const float4* srcB = reinterpret_cast<const float4*>(images + (size_t)(n * CC + c0 + 1) * PX);
    #pragma unroll
    for (int k = 0; k < 4; ++k) {
        int idx = t + k * 256;
        if (idx < PX / 4) {
            float4 a  = srcA[idx];
            float4 bb = srcB[idx];
            int y  = idx / 14;
            int x0 = (idx - y * 14) * 4;
            float4* dst = reinterpret_cast<float4*>(&plane2[y * STRIDE + x0]);
            dst[0] = make_float4(a.x, bb.x, a.y, bb.y);
            dst[1] = make_float4(a.z, bb.z, a.w, bb.w);
        }
    }
    __syncthreads();   // covers list/cnt too

    const int count = cnt;

    // Per-ROI bin-edge tables (e = m*7 + i serves rows and cols).
    for (int e = t; e < count * 7; e += 256) {
        int m = e / 7, i = e - m * 7;
        int r = list[m];
        float4 rv = reinterpret_cast<const float4*>(rois)[r];
        int x1 = (int)floorf(rv.x * (float)WW);
        int y1 = (int)floorf(rv.y * (float)HH);
        int x2 = (int)ceilf (rv.z * (float)WW);
        int y2 = (int)ceilf (rv.w * (float)HH);
        int Hr = y2 - y1, Wr = x2 - x1;
        int sy = y1 + (i * Hr) / 7, ey = y1 + ((i + 1) * Hr + 6) / 7;
        int sx = x1 + (i * Wr) / 7, ex = x1 + ((i + 1) * Wr + 6) / 7;
        ys[m * 7 + i] = (unsigned short)(sy | (ey << 8));
        xs[m * 7 + i] = (unsigned short)(sx | (ex << 8));
    }
    __syncthreads();

    const int wv   = t >> 6;
    const int lane = t & 63;
    const int i = lane / 7;
    const int j = lane - i * 7;

    if (lane < OUTS * OUTS) {
        // (chunk s, wave wv) takes list positions m % 8 == s + 2*wv.
        for (int m = (wv << 1) + s; m < count; m += SPLIT * 4) {
            int r = list[m];
            int yse = ys[m * 7 + i];
            int xse = xs[m * 7 + j];
            int sy = yse & 255, ey = yse >> 8;
            int sx = xse & 255, ex = xse >> 8;

            const float nf = -3.402823466e+38f;  // finfo(float32).min
            float a0 = nf, a1 = nf;

            // 2-row x 4-col chunks; clamped indices re-read edge pixels
            // (duplicates are identity under max). 8 ds_read_b64 per step.
            for (int y = sy; y < ey; y += 2) {
                const float2* r0 = plane2 + y * STRIDE;
                const float2* r1 = plane2 + min(y + 1, ey - 1) * STRIDE;
                for (int x = sx; x < ex; x += 4) {
                    int xb = min(x + 1, ex - 1);
                    int xc = min(x + 2, ex - 1);
                    int xd = min(x + 3, ex - 1);
                    float2 v0 = r0[x],  v1 = r0[xb], v2 = r0[xc], v3 = r0[xd];
                    float2 w0 = r1[x],  w1 = r1[xb], w2 = r1[xc], w3 = r1[xd];
                    a0 = fmaxf(a0, fmaxf(fmaxf(fmaxf(v0.x, v1.x), fmaxf(v2.x, v3.x)),
                                         fmaxf(fmaxf(w0.x, w1.x), fmaxf(w2.x, w3.x))));
                    a1 = fmaxf(a1, fmaxf(fmaxf(fmaxf(v0.y, v1.y), fmaxf(v2.y, v3.y)),
                                         fmaxf(fmaxf(w0.y, w1.y), fmaxf(w2.y, w3.y))));
                }
            }
            size_t o = ((size_t)r * CC + c0) * (OUTS * OUTS) + lane;
            out[o]      = a0;
            out[o + 49] = a1;
        }
    }
}

extern "C" void kernel_launch(void* const* d_in, const int* in_sizes, int n_in,
                              void* d_out, int out_size, void* d_ws, size_t ws_size,
                              hipStream_t stream) {
    const float* images  = (const float*)d_in[0];
    const float* rois    = (const float*)d_in[1];
    const int*   roi_idx = (const int*)d_in[2];
    float* out = (float*)d_out;

    int R = in_sizes[2];                         // 256
    int N = in_sizes[0] / (CC * HH * WW);        // 8

    int grid = N * (CC / 2) * SPLIT;             // 2048 blocks
    roipool_kernel<<<grid, 256, 0, stream>>>(images, rois, roi_idx, out, R);
}